// Round 4
// baseline (181.409 us; speedup 1.0000x reference)
//
#include <hip/hip_runtime.h>
#include <hip/hip_bf16.h>

// NT-Xent loss: z1,z2 [4096,256] fp32 -> scalar loss.
// R4: R3 structure + (a) __launch_bounds__(256,2) so the compiler stops
// compiling for 8-wave occupancy (LDS caps us at 2 waves/SIMD anyway) and
// keeps prefetch registers live -- R3's VGPR=88 showed all prefetches were
// sunk to just-in-time, serializing on L2 latency; (b) explicit 4-deep
// statically-indexed B-fragment rotation (64 VGPRs) with B[0..3] issued
// before the barrier; (c) finisher folded into the GEMM via ticket counter.

#define TWO_N 8192
#define NPAIR 4096
#define DDIM  256
#define NT    64                    // 128-row tiles per dim
#define NBLK  (NT * (NT + 1) / 2)   // 2080 upper-triangle tiles
#define INV_T 2.0f

typedef __attribute__((ext_vector_type(8))) short bf16x8;
typedef __attribute__((ext_vector_type(4))) float f32x4;

typedef __attribute__((address_space(1))) void gvoid_t;
typedef __attribute__((address_space(3))) void lvoid_t;

__device__ __forceinline__ void gload_lds16(const void* g, void* l) {
    __builtin_amdgcn_global_load_lds((gvoid_t*)g, (lvoid_t*)l, 16, 0, 0);
}

// ---------------- Kernel 1: normalize + quantize + pair-dot + zero scratch --
// grid 1024 x 256: one wave per PAIR i (handles rows i and i+4096).
__global__ void k_normalize(const float* __restrict__ z1,
                            const float* __restrict__ z2,
                            __hip_bfloat16* __restrict__ zn,
                            float* __restrict__ e_diag,
                            float* __restrict__ pos,
                            float* __restrict__ row_sumexp,
                            float* __restrict__ out,
                            int* __restrict__ ticket) {
    if (threadIdx.x < 8) row_sumexp[blockIdx.x * 8 + threadIdx.x] = 0.0f;
    if (blockIdx.x == 0 && threadIdx.x == 0) { out[0] = 0.0f; ticket[0] = 0; }

    const int w    = threadIdx.x >> 6;
    const int lane = threadIdx.x & 63;
    const int i    = blockIdx.x * 4 + w;

    float4 a = ((const float4*)(z1 + (size_t)i * DDIM))[lane];
    float4 b = ((const float4*)(z2 + (size_t)i * DDIM))[lane];

    float s1 = a.x * a.x + a.y * a.y + a.z * a.z + a.w * a.w;
    float s2 = b.x * b.x + b.y * b.y + b.z * b.z + b.w * b.w;
    float dd = a.x * b.x + a.y * b.y + a.z * b.z + a.w * b.w;
#pragma unroll
    for (int m = 1; m < 64; m <<= 1) {
        s1 += __shfl_xor(s1, m, 64);
        s2 += __shfl_xor(s2, m, 64);
        dd += __shfl_xor(dd, m, 64);
    }

    float inv1 = 1.0f / fmaxf(sqrtf(s1), 1e-8f);   // matches reference eps
    float inv2 = 1.0f / fmaxf(sqrtf(s2), 1e-8f);

    __hip_bfloat16 q1[4], q2[4];
    q1[0] = __float2bfloat16(a.x * inv1); q1[1] = __float2bfloat16(a.y * inv1);
    q1[2] = __float2bfloat16(a.z * inv1); q1[3] = __float2bfloat16(a.w * inv1);
    q2[0] = __float2bfloat16(b.x * inv2); q2[1] = __float2bfloat16(b.y * inv2);
    q2[2] = __float2bfloat16(b.z * inv2); q2[3] = __float2bfloat16(b.w * inv2);

    float qs1 = 0.0f, qs2 = 0.0f;
#pragma unroll
    for (int j = 0; j < 4; ++j) {
        float f1 = __bfloat162float(q1[j]);
        float f2 = __bfloat162float(q2[j]);
        qs1 += f1 * f1;
        qs2 += f2 * f2;
    }
#pragma unroll
    for (int m = 1; m < 64; m <<= 1) {
        qs1 += __shfl_xor(qs1, m, 64);
        qs2 += __shfl_xor(qs2, m, 64);
    }

    *reinterpret_cast<uint2*>(zn + (size_t)i * DDIM + lane * 4) =
        *reinterpret_cast<uint2*>(q1);
    *reinterpret_cast<uint2*>(zn + (size_t)(i + NPAIR) * DDIM + lane * 4) =
        *reinterpret_cast<uint2*>(q2);

    if (lane == 0) {
        e_diag[i]         = __expf(qs1 * INV_T);   // matches GEMM's bf16 self-dot
        e_diag[i + NPAIR] = __expf(qs2 * INV_T);
        pos[i]            = dd * inv1 * inv2 * INV_T;  // positive-pair term, fp32
    }
}

// ---------------- Kernel 2: symmetric MFMA self-GEMM + exp + row/col sums ----
// 2080 blocks (upper-triangle 128x128 tiles), 256 threads (2x2 waves of 64x64).
// A-tile full K in LDS (XOR-swizzled, verified R3), staged with
// global_load_lds(16B), ONE barrier. B fragments streamed from global with an
// explicit 4-deep register rotation. Last block computes the final loss.
__global__ __launch_bounds__(256, 2)
void k_gemm_sumexp(const __hip_bfloat16* __restrict__ zn,
                   float* __restrict__ row_sumexp,
                   const float* __restrict__ e_diag,
                   const float* __restrict__ pos,
                   float* __restrict__ out,
                   int* __restrict__ ticket) {
    __shared__ __align__(128) __hip_bfloat16 Asmem[128 * DDIM];   // 64 KB

    const int tid  = threadIdx.x;
    const int lane = tid & 63;
    const int w    = tid >> 6;
    const int wr   = w >> 1;          // wave row-half (0/1)
    const int wc   = w & 1;           // wave col-half (0/1)
    const int lr   = lane & 15;
    const int quad = lane >> 4;

    // --- triangular decode: block b -> (rt, ct), rt <= ct (verified R2/R3) ---
    int b  = blockIdx.x;
    int rt = (int)(64.5f - sqrtf(64.5f * 64.5f - 2.0f * (float)b));
    if (rt < 0) rt = 0;
    if (rt > NT - 1) rt = NT - 1;
    while (rt > 0 && NT * rt - (rt * (rt - 1)) / 2 > b) --rt;
    while (NT * (rt + 1) - ((rt + 1) * rt) / 2 <= b) ++rt;
    const int ct   = rt + (b - (NT * rt - (rt * (rt - 1)) / 2));
    const bool diag = (rt == ct);

    const int row_base = rt * 128;
    const int col_base = ct * 128;

    // --- stage A tile (XOR-swizzled, verified R3): 16 rounds of 16B/lane ---
    {
        const int ck = (tid & 24) | ((tid & 7) ^ (tid >> 5));
        const char* gA = (const char*)(zn + (size_t)row_base * DDIM)
                       + (tid >> 5) * (DDIM * 2) + ck * 16;
        char* lA = (char*)Asmem + tid * 16;
#pragma unroll
        for (int j = 0; j < 16; ++j)
            gload_lds16(gA + (size_t)j * 8 * (DDIM * 2), lA + j * 4096);
    }

    // --- B fragment global pointers: row = col_base + wc*64 + ni*16 + lr ---
    const __hip_bfloat16* gB[4];
#pragma unroll
    for (int ni = 0; ni < 4; ++ni)
        gB[ni] = zn + (size_t)(col_base + wc * 64 + ni * 16 + lr) * DDIM + quad * 8;

    // --- issue B prefetch for ksteps 0..3 BEFORE the barrier (overlaps the
    //     A-staging drain; regs stay live across the barrier) ---
    bf16x8 bfb[4][4];
#pragma unroll
    for (int d = 0; d < 4; ++d)
#pragma unroll
        for (int ni = 0; ni < 4; ++ni)
            bfb[d][ni] = *(const bf16x8*)(gB[ni] + d * 32);

    __syncthreads();   // the ONLY barrier (drains A staging + B prefetch)

    // --- A fragment LDS byte offsets (swizzled, verified R3) ---
    int pa[4];
#pragma unroll
    for (int mi = 0; mi < 4; ++mi)
        pa[mi] = (wr * 64 + mi * 16 + lr) * (DDIM * 2) + ((quad ^ (lr & 7)) << 4);

    // A double buffer: ksteps 0 and 1
    bf16x8 afb[2][4];
#pragma unroll
    for (int mi = 0; mi < 4; ++mi)
        afb[0][mi] = *(const bf16x8*)((const char*)Asmem + pa[mi]);
#pragma unroll
    for (int mi = 0; mi < 4; ++mi)
        afb[1][mi] = *(const bf16x8*)((const char*)Asmem + ((pa[mi] ^ 64) + 0));

    f32x4 acc[4][4];
#pragma unroll
    for (int mi = 0; mi < 4; ++mi)
#pragma unroll
        for (int ni = 0; ni < 4; ++ni) acc[mi][ni] = (f32x4){0.f, 0.f, 0.f, 0.f};

#pragma unroll
    for (int k = 0; k < 8; ++k) {
#pragma unroll
        for (int mi = 0; mi < 4; ++mi)
#pragma unroll
            for (int ni = 0; ni < 4; ++ni)
                acc[mi][ni] = __builtin_amdgcn_mfma_f32_16x16x32_bf16(
                    afb[k & 1][mi], bfb[k & 3][ni], acc[mi][ni], 0, 0, 0);
        if (k + 2 < 8) {
            const int kn   = k + 2;
            const int koff = (kn >> 1) << 7;
            const int kx   = (kn & 1) << 6;
#pragma unroll
            for (int mi = 0; mi < 4; ++mi)
                afb[k & 1][mi] =
                    *(const bf16x8*)((const char*)Asmem + ((pa[mi] ^ kx) + koff));
        }
        if (k + 4 < 8) {
#pragma unroll
            for (int ni = 0; ni < 4; ++ni)
                bfb[k & 3][ni] = *(const bf16x8*)(gB[ni] + (k + 4) * 32);
        }
    }

    // --- epilogue: e = exp(2*dot); row-sums always, col-sums if off-diag ---
    // C/D layout (verified R1-R3): col = lane&15, row = quad*4 + reg.
    float rs[4][4];
    float cs[4];
#pragma unroll
    for (int mi = 0; mi < 4; ++mi)
#pragma unroll
        for (int r = 0; r < 4; ++r) rs[mi][r] = 0.0f;
#pragma unroll
    for (int ni = 0; ni < 4; ++ni) cs[ni] = 0.0f;

#pragma unroll
    for (int mi = 0; mi < 4; ++mi)
#pragma unroll
        for (int ni = 0; ni < 4; ++ni)
#pragma unroll
            for (int r = 0; r < 4; ++r) {
                float e = __expf(acc[mi][ni][r] * INV_T);
                rs[mi][r] += e;
                cs[ni] += e;
            }

    // row sums: reduce over lane bits 0..3 (the 16 columns)
#pragma unroll
    for (int mi = 0; mi < 4; ++mi) {
#pragma unroll
        for (int r = 0; r < 4; ++r) {
            float v = rs[mi][r];
            v += __shfl_xor(v, 1, 64);
            v += __shfl_xor(v, 2, 64);
            v += __shfl_xor(v, 4, 64);
            v += __shfl_xor(v, 8, 64);
            if (lr == 0) {
                int row = row_base + wr * 64 + mi * 16 + quad * 4 + r;
                atomicAdd(&row_sumexp[row], v);
            }
        }
    }

    // col sums: reduce over lane bits 4..5
    if (!diag) {
#pragma unroll
        for (int ni = 0; ni < 4; ++ni) {
            float v = cs[ni];
            v += __shfl_xor(v, 16, 64);
            v += __shfl_xor(v, 32, 64);
            if (quad == 0) {
                int col = col_base + wc * 64 + ni * 16 + lr;
                atomicAdd(&row_sumexp[col], v);
            }
        }
    }

    // --- last block computes the final loss (replaces k_final launch) ---
    __syncthreads();            // all waves' atomics drained (vmcnt at barrier)
    __shared__ int s_last;
    if (tid == 0) {
        __threadfence();        // release our atomics device-wide
        int t = __hip_atomic_fetch_add(ticket, 1, __ATOMIC_ACQ_REL,
                                       __HIP_MEMORY_SCOPE_AGENT);
        s_last = (t == NBLK - 1) ? 1 : 0;
    }
    __syncthreads();
    if (s_last) {
        float t = 0.0f;
#pragma unroll
        for (int j = 0; j < 16; ++j) {
            int i = tid + j * 256;   // 0..4095
            float slo = __hip_atomic_load(&row_sumexp[i], __ATOMIC_RELAXED,
                                          __HIP_MEMORY_SCOPE_AGENT);
            float shi = __hip_atomic_load(&row_sumexp[i + NPAIR], __ATOMIC_RELAXED,
                                          __HIP_MEMORY_SCOPE_AGENT);
            t += logf(slo - e_diag[i]) + logf(shi - e_diag[i + NPAIR])
               - 2.0f * pos[i];
        }
#pragma unroll
        for (int m = 1; m < 64; m <<= 1) t += __shfl_xor(t, m, 64);
        __shared__ float ps[4];
        if (lane == 0) ps[w] = t;
        __syncthreads();
        if (tid == 0)
            out[0] = (ps[0] + ps[1] + ps[2] + ps[3]) * (1.0f / (float)TWO_N);
    }
}

extern "C" void kernel_launch(void* const* d_in, const int* in_sizes, int n_in,
                              void* d_out, int out_size, void* d_ws, size_t ws_size,
                              hipStream_t stream) {
    const float* z1 = (const float*)d_in[0];
    const float* z2 = (const float*)d_in[1];
    float* out = (float*)d_out;

    char* ws = (char*)d_ws;
    __hip_bfloat16* zn  = (__hip_bfloat16*)ws;                       // 4 MB
    float* row_sumexp   = (float*)(ws + (size_t)TWO_N * DDIM * 2);   // 32 KB
    float* e_diag       = row_sumexp + TWO_N;                        // 32 KB
    float* pos          = e_diag + TWO_N;                            // 16 KB
    int*   ticket       = (int*)(pos + NPAIR);                       // 4 B

    k_normalize<<<NPAIR / 4, 256, 0, stream>>>(z1, z2, zn, e_diag, pos,
                                               row_sumexp, out, ticket);
    k_gemm_sumexp<<<NBLK, 256, 0, stream>>>(zn, row_sumexp, e_diag, pos,
                                            out, ticket);
}